// Round 10
// baseline (150.660 us; speedup 1.0000x reference)
//
#include <hip/hip_runtime.h>
#include <hip/hip_bf16.h>

#define S_LEN 2048
#define D_DIM 1024

typedef float f32x4 __attribute__((ext_vector_type(4)));
typedef short short8 __attribute__((ext_vector_type(8)));
typedef unsigned short us4 __attribute__((ext_vector_type(4)));
typedef unsigned int u32x4 __attribute__((ext_vector_type(4)));

using bf16 = __hip_bfloat16;

#define GLOBAL_AS(p) ((const __attribute__((address_space(1))) void*)(p))
#define LDS_AS(p) ((__attribute__((address_space(3))) void*)(p))

static __device__ __forceinline__ unsigned short f2bf(float f) {
  bf16 h = __float2bfloat16(f);
  return *reinterpret_cast<unsigned short*>(&h);
}
static __device__ __forceinline__ float bf2f(unsigned short u) {
  unsigned int w = ((unsigned int)u) << 16;
  return __builtin_bit_cast(float, w);
}

// ---------------- mask dtype probe: 0=int32, 1=uint8, 2=float32 ----------------
__global__ void detect_mask_kernel(const unsigned int* __restrict__ m, int* __restrict__ flag) {
  __shared__ int sh;
  if (threadIdx.x == 0) sh = 0;
  __syncthreads();
  int f = 0;
  for (int i = threadIdx.x; i < 4096; i += 256) {
    unsigned int w = m[i];
    if (w == 0x3f800000u) f |= 2;
    if (w & 0xFFFFFF00u) f |= 1;
  }
  if (f) atomicOr(&sh, f);
  __syncthreads();
  if (threadIdx.x == 0) *flag = (sh & 2) ? 2 : ((sh & 1) ? 1 : 0);
}

// ---------------- fused positional-encoding + LayerNorm -> bf16 ----------------
__global__ __launch_bounds__(256) void pe_ln_kernel(
    const float* __restrict__ x, const float* __restrict__ lnw,
    const float* __restrict__ lnb, bf16* __restrict__ out) {
  const int row = blockIdx.x;
  const int s = row & (S_LEN - 1);
  const int tid = threadIdx.x;
  const float pos = (float)s;
  const float* base = x + (size_t)row * D_DIM;

  f32x4 v = *(const f32x4*)(base + tid * 4);
  float h[4];
#pragma unroll
  for (int r = 0; r < 4; ++r) {
    int d = tid * 4 + r;
    float dv = (float)d * (2.0f / 1024.0f);
    float freq = exp2f(dv * -13.287712379549449f);
    float pe = pos * freq;
    float pv = (d & 1) ? __cosf(pe) : __sinf(pe);
    h[r] = pv + v[r];
  }
  float ss = h[0] + h[1] + h[2] + h[3];
#pragma unroll
  for (int o = 32; o >= 1; o >>= 1) ss += __shfl_xor(ss, o);
  __shared__ float red[8];
  const int wave = tid >> 6, lane = tid & 63;
  if (lane == 0) red[wave] = ss;
  __syncthreads();
  const float mu = (red[0] + red[1] + red[2] + red[3]) * (1.0f / 1024.0f);
  float sq = 0.f;
#pragma unroll
  for (int r = 0; r < 4; ++r) { float d0 = h[r] - mu; sq += d0 * d0; }
#pragma unroll
  for (int o = 32; o >= 1; o >>= 1) sq += __shfl_xor(sq, o);
  if (lane == 0) red[4 + wave] = sq;
  __syncthreads();
  const float var = (red[4] + red[5] + red[6] + red[7]) * (1.0f / 1024.0f);
  const float inv = rsqrtf(var + 1e-5f);
  f32x4 wv = *(const f32x4*)(lnw + tid * 4);
  f32x4 bv = *(const f32x4*)(lnb + tid * 4);
  us4 o4;
#pragma unroll
  for (int r = 0; r < 4; ++r) o4[r] = f2bf((h[r] - mu) * inv * wv[r] + bv[r]);
  *(us4*)((unsigned short*)out + (size_t)row * D_DIM + tid * 4) = o4;
}

// ---------------- Wk fp32 [K][N] -> bf16 transposed [N][K] ----------------
__global__ __launch_bounds__(256) void wk_to_bf16t_kernel(const float* __restrict__ wk,
                                                          bf16* __restrict__ wt) {
  __shared__ float t[32][33];
  const int n0 = blockIdx.x * 32, k0 = blockIdx.y * 32;
  const int tx = threadIdx.x & 31, ty = threadIdx.x >> 5;
#pragma unroll
  for (int i = 0; i < 32; i += 8)
    t[ty + i][tx] = wk[(size_t)(k0 + ty + i) * 1024 + n0 + tx];
  __syncthreads();
#pragma unroll
  for (int i = 0; i < 32; i += 8)
    wt[(size_t)(n0 + ty + i) * 1024 + k0 + tx] = __float2bfloat16(t[tx][ty + i]);
}

// ---------------- bf16 GEMM, C = A[M][K] * B_t[N][K]^T  (m201-style phased) ----------
// BM=256, BN=NFR*64, BK=64. 512 threads, 8 waves (2M x 4N); per-wave 128 x NFR*16.
// Per K-tile: NFR==4 -> 4 phases, NFR==2 -> 2 phases; each phase:
//   vmcnt(N) -> s_barrier -> sched_barrier -> stage one 128-row half (2 gload_lds)
//   -> ds_read quadrant frags -> setprio(1) + 16 MFMA + setprio(0).
// Stage order/tile: [B-lo, B-hi, A-lo, A-hi] (NFR4) / [B+A-lo, A-hi] (NFR2).
// Wait audit (per-wave load counting, 2 loads per stage):
//   NFR4 p0 needs A-lo,B (staged prev-tile p2/p0/p1); outstanding 8, newest 2 =
//   A-hi -> vmcnt(2). p1 needs A-hi; outstanding 4, newest 2 = this tile's B-lo
//   -> vmcnt(2). p2/p3 need nothing new -> vmcnt(4)/(8) trivial. Last tile
//   (no staging): [2,0,0,0]. NFR2: [2,4], last [2,0].
// EPI 0: + bias, write bf16 C row-major AND bf16 transposed copy
// EPI 1: * 1/32, write bf16 (mask applied later in softmax)
// EPI 2: plain fp32 write
template <int EPI, int NFR>
__global__ __launch_bounds__(512, 2) void gemm5_kernel(
    const bf16* __restrict__ A, int lda, long long A_bs,
    const bf16* __restrict__ B, int ldb, long long B_bs,
    int K,
    void* __restrict__ C, int ldc, long long C_bs,
    const float* __restrict__ bias, bf16* __restrict__ qkv_t) {
  constexpr int BN = NFR * 64;
  __shared__ bf16 sbuf[2][(256 + BN) * 64];  // A rows [0,256), B at +256*64

  const int tid = threadIdx.x;
  const int wid = tid >> 6, lane = tid & 63;
  const int wm = wid >> 2, wn = wid & 3;  // 2M x 4N wave grid

  // bijective XCD-aware swizzle (all grids = 256 blocks)
  const int gx = gridDim.x, gy = gridDim.y;
  const int nwg = gx * gy * gridDim.z;
  int lin = (blockIdx.z * gy + blockIdx.y) * gx + blockIdx.x;
  lin = (lin & 7) * (nwg >> 3) + (lin >> 3);
  const int bx = lin % gx;
  const int by = (lin / gx) % gy;
  const int z = lin / (gx * gy);

  const int m0 = by * 256;
  const int n0 = bx * BN;

  const bf16* Ab = A + (size_t)z * A_bs;
  const bf16* Bb = B + (size_t)z * B_bs;

  // staging: one gload_lds covers 8 rows x 64k (1 KB); lane L -> row +L>>3,
  // source 16B slot (L&7)^(L>>3); LDS dest linear (reader applies same XOR).
  const int grow = lane >> 3;
  const int gslot = ((lane & 7) ^ grow) * 8;
  const int srow = wid * 16 + grow;  // wave's row inside a 128-row half

  // fragment reads: row r slot s -> linear slot s^(r&7)
  const int lrow = lane & 15;
  const int slot0 = ((lane >> 4) ^ (lrow & 7)) * 8;
  const int slot1 = (((lane >> 4) + 4) ^ (lrow & 7)) * 8;
  const int rdA = (wm * 128 + lrow) * 64;
  const int rdB = 16384 + (wn * (NFR * 16) + lrow) * 64;

  f32x4 acc[8][NFR];
#pragma unroll
  for (int i = 0; i < 8; ++i)
#pragma unroll
    for (int j = 0; j < NFR; ++j) acc[i][j] = (f32x4)(0.0f);

  short8 af[4][2], bfr[2][2];

#define STAGE_A_H(D, kk, hb)                                                      \
  do {                                                                            \
    _Pragma("unroll")                                                             \
    for (int i_ = 0; i_ < 2; ++i_)                                                \
      __builtin_amdgcn_global_load_lds(                                           \
          GLOBAL_AS(Ab + (size_t)(m0 + (hb) + srow + i_ * 8) * lda + gslot + (kk)),\
          LDS_AS(&(D)[((hb) + wid * 16 + i_ * 8) * 64]), 16, 0, 0);               \
  } while (0)
#define STAGE_B_H(D, kk, hb)                                                      \
  do {                                                                            \
    _Pragma("unroll")                                                             \
    for (int i_ = 0; i_ < 2; ++i_)                                                \
      __builtin_amdgcn_global_load_lds(                                           \
          GLOBAL_AS(Bb + (size_t)(n0 + (hb) + srow + i_ * 8) * ldb + gslot + (kk)),\
          LDS_AS(&(D)[16384 + ((hb) + wid * 16 + i_ * 8) * 64]), 16, 0, 0);       \
  } while (0)
#define READ_A(S, rh)                                                             \
  do {                                                                            \
    _Pragma("unroll")                                                             \
    for (int m_ = 0; m_ < 4; ++m_) {                                              \
      const bf16* p_ = (S) + rdA + ((rh) * 64 + m_ * 16) * 64;                    \
      af[m_][0] = *(const short8*)(p_ + slot0);                                   \
      af[m_][1] = *(const short8*)(p_ + slot1);                                   \
    }                                                                             \
  } while (0)
#define READ_B(S, nf0)                                                            \
  do {                                                                            \
    _Pragma("unroll")                                                             \
    for (int n_ = 0; n_ < 2; ++n_) {                                              \
      const bf16* p_ = (S) + rdB + (((nf0) + n_) * 16) * 64;                      \
      bfr[n_][0] = *(const short8*)(p_ + slot0);                                  \
      bfr[n_][1] = *(const short8*)(p_ + slot1);                                  \
    }                                                                             \
  } while (0)
#define MFMA_Q(rh, nf0)                                                           \
  do {                                                                            \
    __builtin_amdgcn_s_setprio(1);                                                \
    _Pragma("unroll")                                                             \
    for (int h_ = 0; h_ < 2; ++h_)                                                \
      _Pragma("unroll")                                                           \
      for (int m_ = 0; m_ < 4; ++m_)                                              \
        _Pragma("unroll")                                                         \
        for (int n_ = 0; n_ < 2; ++n_)                                            \
          acc[(rh) * 4 + m_][(nf0) + n_] =                                        \
              __builtin_amdgcn_mfma_f32_16x16x32_bf16(                            \
                  af[m_][h_], bfr[n_][h_], acc[(rh) * 4 + m_][(nf0) + n_], 0, 0, 0); \
    __builtin_amdgcn_s_setprio(0);                                                \
  } while (0)
#define WAITB(n)                                                                  \
  do {                                                                            \
    asm volatile("s_waitcnt vmcnt(" #n ")" ::: "memory");                         \
    __builtin_amdgcn_s_barrier();                                                 \
    __builtin_amdgcn_sched_barrier(0);                                            \
  } while (0)

  const int NT = K >> 6;
  // prologue: stage tile 0 fully into buf 0, drain
  {
    bf16* D = &sbuf[0][0];
    STAGE_B_H(D, 0, 0);
    if constexpr (NFR == 4) STAGE_B_H(D, 0, 128);
    STAGE_A_H(D, 0, 0);
    STAGE_A_H(D, 0, 128);
    WAITB(0);
  }
#pragma unroll 1
  for (int kt = 0; kt < NT; ++kt) {
    const bf16* S = &sbuf[kt & 1][0];
    bf16* D = &sbuf[(kt & 1) ^ 1][0];
    const bool pf = (kt + 1 < NT);
    const size_t kk = (size_t)(kt + 1) * 64;
    if constexpr (NFR == 4) {
      // phase 0: quadrant (rh0, ch0); stage B-lo of next tile
      WAITB(2);
      if (pf) STAGE_B_H(D, kk, 0);
      READ_A(S, 0);
      READ_B(S, 0);
      MFMA_Q(0, 0);
      // phase 1: (rh1, ch0); stage B-hi
      if (pf) { WAITB(2); } else { WAITB(0); }
      if (pf) STAGE_B_H(D, kk, 128);
      READ_A(S, 1);
      MFMA_Q(1, 0);
      // phase 2: (rh1, ch1); stage A-lo
      if (pf) { WAITB(4); } else { WAITB(0); }
      if (pf) STAGE_A_H(D, kk, 0);
      READ_B(S, 2);
      MFMA_Q(1, 2);
      // phase 3: (rh0, ch1); stage A-hi
      if (pf) { WAITB(8); } else { WAITB(0); }
      if (pf) STAGE_A_H(D, kk, 128);
      READ_A(S, 0);
      MFMA_Q(0, 2);
    } else {
      // phase 0: row-half 0, all cols; stage B + A-lo of next tile
      WAITB(2);
      if (pf) { STAGE_B_H(D, kk, 0); STAGE_A_H(D, kk, 0); }
      READ_A(S, 0);
      READ_B(S, 0);
      MFMA_Q(0, 0);
      // phase 1: row-half 1; stage A-hi
      if (pf) { WAITB(4); } else { WAITB(0); }
      if (pf) STAGE_A_H(D, kk, 128);
      READ_A(S, 1);
      MFMA_Q(1, 0);
    }
  }
#undef STAGE_A_H
#undef STAGE_B_H
#undef READ_A
#undef READ_B
#undef MFMA_Q
#undef WAITB

  // epilogue: C/D layout col = lane&15, row = (lane>>4)*4 + reg  [measured m89]
  const int r0 = (lane >> 4) * 4;
#pragma unroll
  for (int i = 0; i < 8; ++i) {
    const int rowl = m0 + wm * 128 + i * 16 + r0;
#pragma unroll
    for (int j = 0; j < NFR; ++j) {
      const int col = n0 + wn * NFR * 16 + j * 16 + lrow;
      if (EPI == 0) {
        const float bv = bias[col];
        us4 pack;
#pragma unroll
        for (int r = 0; r < 4; ++r) {
          unsigned short hb = f2bf(acc[i][j][r] + bv);
          ((unsigned short*)C)[(size_t)(rowl + r) * ldc + col] = hb;
          pack[r] = hb;
        }
        const int bb = rowl >> 11, s = rowl & 2047;
        *(us4*)((unsigned short*)qkv_t + (size_t)bb * (1024ll * 2048) +
                (size_t)col * 2048 + s) = pack;
      } else if (EPI == 1) {
        unsigned short* Cb = (unsigned short*)C + (size_t)z * C_bs;
#pragma unroll
        for (int r = 0; r < 4; ++r)
          Cb[(size_t)(rowl + r) * ldc + col] = f2bf(acc[i][j][r] * 0.03125f);
      } else {
#pragma unroll
        for (int r = 0; r < 4; ++r)
          ((float*)C + (size_t)z * C_bs)[(size_t)(rowl + r) * ldc + col] = acc[i][j][r];
      }
    }
  }
}

// ---------------- fused mask + in-place row softmax on bf16 scores ----------------
__global__ __launch_bounds__(256) void softmax_kernel(
    unsigned short* __restrict__ scores, const void* __restrict__ mask,
    const int* __restrict__ flagp) {
  const int row = blockIdx.x;  // 8192 rows = b*2048 + q
  const int fmode = *flagp;
  unsigned short* base = scores + (size_t)row * 2048;
  const int tid = threadIdx.x;
  const int wave = tid >> 6, lane = tid & 63;

  short8 v = *(const short8*)(base + tid * 8);
  float x[8];
#pragma unroll
  for (int r = 0; r < 8; ++r) x[r] = bf2f((unsigned short)v[r]);

  const size_t mofs = (size_t)row * 2048 + tid * 8;
  if (fmode == 0) {
    const unsigned int* mp = (const unsigned int*)mask + mofs;
    u32x4 m0 = *(const u32x4*)mp;
    u32x4 m1 = *(const u32x4*)(mp + 4);
#pragma unroll
    for (int r = 0; r < 4; ++r) { if (m0[r]) x[r] = 1e-9f; }
#pragma unroll
    for (int r = 0; r < 4; ++r) { if (m1[r]) x[4 + r] = 1e-9f; }
  } else if (fmode == 1) {
    const unsigned char* mp = (const unsigned char*)mask + mofs;
    us4 mb = *(const us4*)mp;  // 8 bytes
#pragma unroll
    for (int r = 0; r < 4; ++r) {
      if (mb[r] & 0x00FF) x[2 * r] = 1e-9f;
      if (mb[r] & 0xFF00) x[2 * r + 1] = 1e-9f;
    }
  } else {
    const float* mp = (const float*)mask + mofs;
    f32x4 m0 = *(const f32x4*)mp;
    f32x4 m1 = *(const f32x4*)(mp + 4);
#pragma unroll
    for (int r = 0; r < 4; ++r) { if (m0[r] != 0.0f) x[r] = 1e-9f; }
#pragma unroll
    for (int r = 0; r < 4; ++r) { if (m1[r] != 0.0f) x[4 + r] = 1e-9f; }
  }

  float m = x[0];
#pragma unroll
  for (int r = 1; r < 8; ++r) m = fmaxf(m, x[r]);
#pragma unroll
  for (int o = 32; o >= 1; o >>= 1) m = fmaxf(m, __shfl_xor(m, o));
  __shared__ float red[8];
  if (lane == 0) red[wave] = m;
  __syncthreads();
  m = fmaxf(fmaxf(red[0], red[1]), fmaxf(red[2], red[3]));
  float e[8], sum = 0.f;
#pragma unroll
  for (int r = 0; r < 8; ++r) { e[r] = expf(x[r] - m); sum += e[r]; }
#pragma unroll
  for (int o = 32; o >= 1; o >>= 1) sum += __shfl_xor(sum, o);
  if (lane == 0) red[4 + wave] = sum;
  __syncthreads();
  const float inv = 1.0f / (red[4] + red[5] + red[6] + red[7]);
  short8 o8;
#pragma unroll
  for (int r = 0; r < 8; ++r) o8[r] = (short)f2bf(e[r] * inv);
  *(short8*)(base + tid * 8) = o8;
}

// ---------------- launcher ----------------
extern "C" void kernel_launch(void* const* d_in, const int* in_sizes, int n_in,
                              void* d_out, int out_size, void* d_ws, size_t ws_size,
                              hipStream_t stream) {
  const float* tensor = (const float*)d_in[0];
  const void* mask = d_in[1];
  const float* lnw = (const float*)d_in[2];
  const float* lnb = (const float*)d_in[3];
  const float* wk = (const float*)d_in[4];
  const float* bk = (const float*)d_in[5];
  float* out = (float*)d_out;

  // ws layout (bytes):
  //   0     : Wk_t bf16 [1024][1024]                    (2 MB)
  //   2 MB  : qkv_n bf16 [8192][1024]                   (16 MB)
  //   18 MB : qkv_t bf16 [4][1024][2048]                (16 MB)
  //   34 MB : x bf16 (dead after gemm0) / scores bf16 [4][2048][2048] (32 MB)
  //   66 MB : mask-dtype flag                            (4 B)
  char* ws = (char*)d_ws;
  bf16* wkt = (bf16*)(ws);
  bf16* qkvn = (bf16*)(ws + (2ll << 20));
  bf16* qkvt = (bf16*)(ws + (18ll << 20));
  bf16* xbf = (bf16*)(ws + (34ll << 20));
  unsigned short* scores = (unsigned short*)(ws + (34ll << 20));
  int* flag = (int*)(ws + (66ll << 20));

  detect_mask_kernel<<<1, 256, 0, stream>>>((const unsigned int*)mask, flag);
  pe_ln_kernel<<<8192, 256, 0, stream>>>(tensor, lnw, lnb, xbf);
  wk_to_bf16t_kernel<<<dim3(32, 32), 256, 0, stream>>>(wk, wkt);

  // qkv = x @ Wk + bk  (M=8192, N=1024, K=1024): 8x32 = 256 blocks, 1/CU
  gemm5_kernel<0, 2><<<dim3(8, 32, 1), 512, 0, stream>>>(
      xbf, 1024, 0, wkt, 1024, 0, 1024,
      (void*)qkvn, 1024, 0, bk, qkvt);

  // scores = qkv @ qkv^T / 32, bf16  (M=N=2048, K=1024, 4 batches): 8x8x4 = 256
  gemm5_kernel<1, 4><<<dim3(8, 8, 4), 512, 0, stream>>>(
      qkvn, 1024, 2048ll * 1024,
      qkvn, 1024, 2048ll * 1024, 1024,
      (void*)scores, 2048, 2048ll * 2048, nullptr, nullptr);

  // fused mask-fill(1e-9) + softmax rows, in-place bf16 -> bf16
  softmax_kernel<<<8192, 256, 0, stream>>>(scores, mask, flag);

  // out = weights @ qkv  (M=2048, N=1024, K=2048, 4 batches): 8x8x4 = 256
  gemm5_kernel<2, 2><<<dim3(8, 8, 4), 512, 0, stream>>>(
      (const bf16*)scores, 2048, 2048ll * 2048,
      qkvt, 2048, 1024ll * 2048, 2048,
      (void*)out, 1024, 2048ll * 1024,
      nullptr, nullptr);
}